// Round 1
// baseline (570.884 us; speedup 1.0000x reference)
//
#include <hip/hip_runtime.h>
#include <hip/hip_fp16.h>

#define N_NODES 100000
#define N_EDGES 1600000
#define N_GRAPHS 1024
#define DIM_IN 128
#define D1 100
#define D1P 128            // padded p1 row (halves) -> 256 B, 2 aligned cache lines
#define D2 20
#define D2P 32             // padded p2 row (halves) -> 64 B, 1 cache line
#define DIM_SF 32
#define DF1 128
#define DF2 32
#define DOUT 8
#define EPS 1e-5f

// ---------------- bucket-sort CSR build ----------------
#define NBK 512                 // buckets
#define BW 196                  // nodes per bucket (512*196 = 100352 >= N_NODES)
#define EPB 4096                // edges per block in pass 1
#define NBLK1 ((N_EDGES + EPB - 1) / EPB)   // 391

// pass 1a: per-(block,bucket) histogram. No global atomics.
__global__ void __launch_bounds__(256) k_bcount(const int* __restrict__ dst,
                                                int* __restrict__ counts) {
  __shared__ int hist[NBK];
  int t = threadIdx.x, blk = blockIdx.x;
  for (int i = t; i < NBK; i += 256) hist[i] = 0;
  __syncthreads();
  int base = blk * EPB;
#pragma unroll
  for (int r = 0; r < 16; r++) {
    int e = base + r * 256 + t;
    if (e < N_EDGES) {
      unsigned b = (unsigned)dst[e] / BW;
      atomicAdd(&hist[b], 1);
    }
  }
  __syncthreads();
  for (int i = t; i < NBK; i += 256) counts[blk * NBK + i] = hist[i];
}

// pass 1b: for each bucket, exclusive scan of counts across blocks. 1 wave/bucket.
__global__ void __launch_bounds__(64) k_bscanA(const int* __restrict__ counts,
                                               int* __restrict__ offs,
                                               int* __restrict__ totals) {
  int b = blockIdx.x, l = threadIdx.x;
  int carry = 0;
  for (int chunk = 0; chunk < NBLK1; chunk += 64) {
    int blk = chunk + l;
    int v = (blk < NBLK1) ? counts[blk * NBK + b] : 0;
    int incl = v;
    for (int s = 1; s < 64; s <<= 1) { int x = __shfl_up(incl, s); if (l >= s) incl += x; }
    if (blk < NBLK1) offs[blk * NBK + b] = carry + incl - v;
    carry += __shfl(incl, 63);
  }
  if (l == 0) totals[b] = carry;
}

// pass 1c: exclusive scan of bucket totals -> bucket base offsets (513 entries).
__global__ void __launch_bounds__(512) k_bscanB(const int* __restrict__ totals,
                                                int* __restrict__ bin_base) {
  __shared__ int lds[NBK];
  int t = threadIdx.x;
  int v = totals[t];
  lds[t] = v; __syncthreads();
  for (int s = 1; s < NBK; s <<= 1) {
    int x = (t >= s) ? lds[t - s] : 0;
    __syncthreads();
    lds[t] += x;
    __syncthreads();
  }
  bin_base[t] = lds[t] - v;
  if (t == NBK - 1) bin_base[NBK] = lds[t];
}

// pass 1d: scatter packed (src<<8 | local_dst) into bucket-ordered array.
__global__ void __launch_bounds__(256) k_bscatter(const int* __restrict__ src,
                                                  const int* __restrict__ dst,
                                                  const int* __restrict__ offs,
                                                  const int* __restrict__ bin_base,
                                                  unsigned* __restrict__ packed_out) {
  __shared__ int hist[NBK];
  __shared__ int lbase[NBK];
  __shared__ int gbase[NBK];
  __shared__ int ssum[256];
  __shared__ unsigned sval[EPB];   // 16 KB
  __shared__ int spos[EPB];        // 16 KB
  int t = threadIdx.x, blk = blockIdx.x;
  for (int i = t; i < NBK; i += 256) hist[i] = 0;
  __syncthreads();
  int base = blk * EPB;
  unsigned pk[16]; int bn[16]; int rk[16];
#pragma unroll
  for (int r = 0; r < 16; r++) {
    int e = base + r * 256 + t;
    bn[r] = -1;
    if (e < N_EDGES) {
      int dv = dst[e];
      unsigned b = (unsigned)dv / BW;
      unsigned ld = (unsigned)dv - b * BW;
      bn[r] = (int)b;
      pk[r] = ((unsigned)src[e] << 8) | ld;
      rk[r] = atomicAdd(&hist[b], 1);
    }
  }
  __syncthreads();
  int h0 = hist[2 * t], h1 = hist[2 * t + 1];
  int s = h0 + h1;
  ssum[t] = s; __syncthreads();
  for (int off = 1; off < 256; off <<= 1) {
    int x = (t >= off) ? ssum[t - off] : 0;
    __syncthreads();
    ssum[t] += x;
    __syncthreads();
  }
  int excl = ssum[t] - s;
  lbase[2 * t] = excl;
  lbase[2 * t + 1] = excl + h0;
  gbase[2 * t]     = bin_base[2 * t]     + offs[blk * NBK + 2 * t];
  gbase[2 * t + 1] = bin_base[2 * t + 1] + offs[blk * NBK + 2 * t + 1];
  __syncthreads();
#pragma unroll
  for (int r = 0; r < 16; r++) {
    if (bn[r] >= 0) {
      int li = lbase[bn[r]] + rk[r];
      sval[li] = pk[r];
      spos[li] = gbase[bn[r]] + rk[r];
    }
  }
  __syncthreads();
  int cnt = N_EDGES - base; if (cnt > EPB) cnt = EPB;
  for (int i = t; i < cnt; i += 256) packed_out[spos[i]] = sval[i];
}

// pass 2: one block per bucket. Sort within bucket in LDS, emit exact CSR.
__global__ void __launch_bounds__(256) k_bfine(const unsigned* __restrict__ packed_in,
                                               const int* __restrict__ bin_base,
                                               int* __restrict__ csr,
                                               int* __restrict__ deg,
                                               int* __restrict__ row_off) {
  __shared__ unsigned sval[EPB];   // 16 KB
  __shared__ int scsr[EPB];        // 16 KB
  __shared__ int hist[256];
  __shared__ int soff[256];
  __shared__ int cur[256];
  int b = blockIdx.x, t = threadIdx.x;
  int start = bin_base[b];
  int cnt = bin_base[b + 1] - start;
  if (cnt > EPB) cnt = EPB;
  hist[t] = 0;
  __syncthreads();
  for (int i = t; i < cnt; i += 256) {
    unsigned v = packed_in[start + i];
    sval[i] = v;
    atomicAdd(&hist[v & 255u], 1);
  }
  __syncthreads();
  int h = hist[t];
  soff[t] = h; __syncthreads();
  for (int off = 1; off < 256; off <<= 1) {
    int x = (t >= off) ? soff[t - off] : 0;
    __syncthreads();
    soff[t] += x;
    __syncthreads();
  }
  int excl = soff[t] - h;
  cur[t] = excl;
  int n = b * BW + t;
  if (t < BW && n < N_NODES) { deg[n] = h; row_off[n] = start + excl; }
  __syncthreads();
  for (int i = t; i < cnt; i += 256) {
    unsigned v = sval[i];
    int pos = atomicAdd(&cur[v & 255u], 1);
    scsr[pos] = (int)(v >> 8);
  }
  __syncthreads();
  for (int i = t; i < cnt; i += 256) csr[start + i] = scsr[i];
}

// ---------------- p1 = fp16(feat @ W1), rows padded to D1P=128 halves ----------------
// Pad columns 100..127 are left uninitialized; every consumer discards them.
__global__ void __launch_bounds__(256) k_gemm1(const float* __restrict__ feat,
                                               const float* __restrict__ W1,
                                               __half* __restrict__ p1h) {
  __shared__ float w1s[DIM_IN * D1];   // 51.2 KB
  int t = threadIdx.x;
  for (int i = t; i < DIM_IN * D1; i += 256) w1s[i] = W1[i];
  __syncthreads();
  if (t >= 250) return;
  int q = t % 25, ng = t / 25;
  int n0 = blockIdx.x * 40 + ng * 4;   // grid 2500 -> exactly 100000 nodes
  int c0 = q * 4;
  float acc[4][4] = {{0.f}};
  const float* f0 = feat + (size_t)n0 * DIM_IN;
  for (int k = 0; k < DIM_IN; k += 4) {
    float4 w0 = *(const float4*)&w1s[(k + 0) * D1 + c0];
    float4 w1 = *(const float4*)&w1s[(k + 1) * D1 + c0];
    float4 w2 = *(const float4*)&w1s[(k + 2) * D1 + c0];
    float4 w3 = *(const float4*)&w1s[(k + 3) * D1 + c0];
#pragma unroll
    for (int j = 0; j < 4; j++) {
      float4 f = *(const float4*)(f0 + j * DIM_IN + k);
      acc[j][0] += f.x * w0.x + f.y * w1.x + f.z * w2.x + f.w * w3.x;
      acc[j][1] += f.x * w0.y + f.y * w1.y + f.z * w2.y + f.w * w3.y;
      acc[j][2] += f.x * w0.z + f.y * w1.z + f.z * w2.z + f.w * w3.z;
      acc[j][3] += f.x * w0.w + f.y * w1.w + f.z * w2.w + f.w * w3.w;
    }
  }
#pragma unroll
  for (int j = 0; j < 4; j++) {
    __half2* d2 = (__half2*)(p1h + (size_t)(n0 + j) * D1P + c0);
    d2[0] = __floats2half2_rn(acc[j][0], acc[j][1]);
    d2[1] = __floats2half2_rn(acc[j][2], acc[j][3]);
  }
}

__device__ __forceinline__ void acc8(int4 raw, float4& A, float4& B) {
  const __half2* h = (const __half2*)&raw;
  float2 f0 = __half22float2(h[0]);
  float2 f1 = __half22float2(h[1]);
  float2 f2 = __half22float2(h[2]);
  float2 f3 = __half22float2(h[3]);
  A.x += f0.x; A.y += f0.y; A.z += f1.x; A.w += f1.y;
  B.x += f2.x; B.y += f2.y; B.z += f3.x; B.w += f3.y;
}

// ---------- agg1: wave-per-node gather (4 edges per dwordx4 round) + b1 + relu + GEMM2 ----------
__global__ void __launch_bounds__(256) k_agg1(const __half* __restrict__ p1h,
                                              const int* __restrict__ deg,
                                              const int* __restrict__ row_off,
                                              const int* __restrict__ csr,
                                              const float* __restrict__ b1,
                                              const float* __restrict__ W2,
                                              __half* __restrict__ p2h) {
  __shared__ float w2s[D1 * D2];
  __shared__ float b1s[D1];
  __shared__ float hbuf[4][104];
  int t = threadIdx.x;
  for (int i = t; i < D1 * D2; i += 256) w2s[i] = W2[i];
  if (t < D1) b1s[t] = b1[t];
  __syncthreads();
  int w = t >> 6, lane = t & 63;
  int n = blockIdx.x * 4 + w;
  int g = lane >> 4, o = lane & 15;         // 4 edge-slots x 16B-slots; lane covers ch 8o..8o+7
  int d = deg[n], ro = row_off[n];
  float4 A = {0.f, 0.f, 0.f, 0.f}, B = {0.f, 0.f, 0.f, 0.f};
  const size_t obyte = (size_t)(o * 8);     // halves offset within row
  if (d > 0) {
    for (int base = 0; base < d; base += 64) {
      int m = d - base; if (m > 64) m = 64;
      int sv = (lane < m) ? csr[ro + base + lane] : 0;
      int nr = m >> 2;
      int r = 0;
      for (; r + 1 < nr; r += 2) {          // 8 edges in flight
        int sA = __shfl(sv, r * 4 + g);
        int sB = __shfl(sv, r * 4 + 4 + g);
        int4 ra = *(const int4*)(p1h + (size_t)sA * D1P + obyte);
        int4 rb = *(const int4*)(p1h + (size_t)sB * D1P + obyte);
        acc8(ra, A, B);
        acc8(rb, A, B);
      }
      if (r < nr) {
        int sA = __shfl(sv, r * 4 + g);
        int4 ra = *(const int4*)(p1h + (size_t)sA * D1P + obyte);
        acc8(ra, A, B);
      }
      int rem = m & 3;
      int sT = __shfl(sv, nr * 4 + g);      // hoisted out of divergent branch
      if (rem && g < rem) {
        int4 ra = *(const int4*)(p1h + (size_t)sT * D1P + obyte);
        acc8(ra, A, B);
      }
    }
  } else {
    if (g == 0) {                           // deg==0: agg = own p1 row
      int4 ra = *(const int4*)(p1h + (size_t)n * D1P + obyte);
      acc8(ra, A, B);
    }
  }
  // reduce the 4 edge-groups: lanes {o, o+16, o+32, o+48} -> lane o
  float v[8] = {A.x, A.y, A.z, A.w, B.x, B.y, B.z, B.w};
#pragma unroll
  for (int j = 0; j < 8; j++) {
    v[j] += __shfl_down(v[j], 32);
    v[j] += __shfl_down(v[j], 16);
  }
  if (lane < 13) {
    float inv = (d > 0) ? 1.0f / (float)d : 1.0f;
#pragma unroll
    for (int j = 0; j < 8; j++) {
      int ch = 8 * lane + j;
      if (ch < D1) hbuf[w][ch] = fmaxf(v[j] * inv + b1s[ch], 0.f);
    }
  }
  __syncthreads();
  // GEMM2: 3 lane-groups of 20 split the 100-dot; 2-shuffle reduce.
  int p = lane / 20;                        // 0..3 (p==3 idle)
  int j20 = lane - p * 20;
  int cbeg = p * 33 + (p > 0);              // 0,34,67,100
  int cend = (p + 1) * 33 + 1;              // 34,67,100,133
  if (cend > D1) cend = D1;
  float acc = 0.f;
  for (int c = cbeg; c < cend; c++) acc += hbuf[w][c] * w2s[c * D2 + j20];
  float t1 = __shfl_down(acc, 20);
  float t2 = __shfl_down(acc, 40);
  acc += t1 + t2;
  if (lane < D2)       p2h[(size_t)n * D2P + lane] = __float2half_rn(acc);
  else if (lane < D2P) p2h[(size_t)n * D2P + lane] = __float2half_rn(0.f);
}

__device__ __forceinline__ void acc4(int2 raw, float4& A) {
  const __half2* h = (const __half2*)&raw;
  float2 f0 = __half22float2(h[0]);
  float2 f1 = __half22float2(h[1]);
  A.x += f0.x; A.y += f0.y; A.z += f1.x; A.w += f1.y;
}

// ---------- agg2: wave-per-node gather (8 edges per b64 round) + b2 + relu + pool ----------
__global__ void __launch_bounds__(256) k_agg2(const __half* __restrict__ p2h,
                                              const int* __restrict__ deg,
                                              const int* __restrict__ row_off,
                                              const int* __restrict__ csr,
                                              const float* __restrict__ b2,
                                              const int* __restrict__ n2g,
                                              float* __restrict__ hg_sum,
                                              int* __restrict__ gcnt) {
  int t = threadIdx.x, w = t >> 6, lane = t & 63;
  int n = blockIdx.x * 4 + w;
  int g8 = lane >> 3, o = lane & 7;         // 8 edge-slots x 8B-slots; lane covers ch 4o..4o+3
  int d = deg[n], ro = row_off[n];
  float4 A = {0.f, 0.f, 0.f, 0.f};
  const size_t obyte = (size_t)(o * 4);     // halves offset within row
  if (d > 0) {
    for (int base = 0; base < d; base += 64) {
      int m = d - base; if (m > 64) m = 64;
      int sv = (lane < m) ? csr[ro + base + lane] : 0;
      int nr = m >> 3;
      int r = 0;
      for (; r + 1 < nr; r += 2) {          // 16 edges in flight
        int sA = __shfl(sv, r * 8 + g8);
        int sB = __shfl(sv, r * 8 + 8 + g8);
        int2 ra = *(const int2*)(p2h + (size_t)sA * D2P + obyte);
        int2 rb = *(const int2*)(p2h + (size_t)sB * D2P + obyte);
        acc4(ra, A);
        acc4(rb, A);
      }
      if (r < nr) {
        int sA = __shfl(sv, r * 8 + g8);
        int2 ra = *(const int2*)(p2h + (size_t)sA * D2P + obyte);
        acc4(ra, A);
      }
      int rem = m & 7;
      int sT = __shfl(sv, nr * 8 + g8);     // hoisted out of divergent branch
      if (rem && g8 < rem) {
        int2 ra = *(const int2*)(p2h + (size_t)sT * D2P + obyte);
        acc4(ra, A);
      }
    }
  } else {
    if (g8 == 0) {
      int2 ra = *(const int2*)(p2h + (size_t)n * D2P + obyte);
      acc4(ra, A);
    }
  }
  // reduce the 8 edge-groups: lanes {o, o+8, ..., o+56} -> lane o
  float v[4] = {A.x, A.y, A.z, A.w};
#pragma unroll
  for (int j = 0; j < 4; j++) {
    v[j] += __shfl_down(v[j], 32);
    v[j] += __shfl_down(v[j], 16);
    v[j] += __shfl_down(v[j], 8);
  }
  if (lane < 5) {
    float inv = (d > 0) ? 1.0f / (float)d : 1.0f;
    int gg = n2g[n];
#pragma unroll
    for (int j = 0; j < 4; j++) {
      int ch = 4 * lane + j;
      float val = fmaxf(v[j] * inv + b2[ch], 0.f);
      atomicAdd(&hg_sum[gg * D2 + ch], val);
    }
  }
  if (lane == 0) atomicAdd(&gcnt[n2g[n]], 1);
}

// ---------- head ----------
__global__ void __launch_bounds__(128) k_mlp1(const float* __restrict__ hg_sum,
                                              const int* __restrict__ gcnt,
                                              const float* __restrict__ sf,
                                              const float* __restrict__ Wf1,
                                              const float* __restrict__ bf1,
                                              float* __restrict__ y1) {
  __shared__ float prod[D2 * DIM_SF];
  __shared__ float hgl[D2], sfl[DIM_SF];
  int g = blockIdx.x, t = threadIdx.x;
  float cnt = (float)gcnt[g]; if (cnt < 1.f) cnt = 1.f;
  if (t < D2) hgl[t] = hg_sum[g * D2 + t] / cnt;
  if (t < DIM_SF) sfl[t] = sf[g * DIM_SF + t];
  __syncthreads();
  for (int i = t; i < D2 * DIM_SF; i += 128) prod[i] = hgl[i >> 5] * sfl[i & 31];
  __syncthreads();
  float acc = bf1[t];
#pragma unroll 4
  for (int k = 0; k < D2 * DIM_SF; k++) acc += prod[k] * Wf1[k * DF1 + t];
  y1[g * DF1 + t] = acc;
}

__global__ void k_bnstats(const float* __restrict__ x, int ld,
                          float* __restrict__ mu, float* __restrict__ rstd) {
  __shared__ float ssum[256], ssq[256];
  int c = blockIdx.x, t = threadIdx.x;
  float s = 0.f, q = 0.f;
  for (int r = t; r < N_GRAPHS; r += 256) { float v = x[r * ld + c]; s += v; q += v * v; }
  ssum[t] = s; ssq[t] = q; __syncthreads();
  for (int off = 128; off > 0; off >>= 1) {
    if (t < off) { ssum[t] += ssum[t + off]; ssq[t] += ssq[t + off]; }
    __syncthreads();
  }
  if (t == 0) {
    float m = ssum[0] / (float)N_GRAPHS;
    float var = ssq[0] / (float)N_GRAPHS - m * m;
    mu[c] = m;
    rstd[c] = rsqrtf(var + EPS);
  }
}

__global__ void k_mlp2(const float* __restrict__ y1, const float* __restrict__ mu1,
                       const float* __restrict__ rstd1, const float* __restrict__ g1,
                       const float* __restrict__ be1, const float* __restrict__ Wf2,
                       const float* __restrict__ bf2, float* __restrict__ y2) {
  int idx = blockIdx.x * 256 + threadIdx.x;
  int g = idx >> 5, o = idx & 31;
  float acc = bf2[o];
  for (int k = 0; k < DF1; k++) {
    float x = (y1[g * DF1 + k] - mu1[k]) * rstd1[k] * g1[k] + be1[k];
    x = fmaxf(x, 0.f);
    acc += x * Wf2[k * DF2 + o];
  }
  y2[g * DF2 + o] = acc;
}

__global__ void k_mlp3(const float* __restrict__ y2, const float* __restrict__ mu2,
                       const float* __restrict__ rstd2, const float* __restrict__ g2,
                       const float* __restrict__ be2, const float* __restrict__ Wf3,
                       const float* __restrict__ bf3, float* __restrict__ out) {
  int idx = blockIdx.x * 256 + threadIdx.x;
  int g = idx >> 3, o = idx & 7;
  float acc = bf3[o];
  for (int k = 0; k < DF2; k++) {
    float x = (y2[g * DF2 + k] - mu2[k]) * rstd2[k] * g2[k] + be2[k];
    x = fmaxf(x, 0.f);
    acc += x * Wf3[k * DOUT + o];
  }
  out[g * DOUT + o] = acc;
}

extern "C" void kernel_launch(void* const* d_in, const int* in_sizes, int n_in,
                              void* d_out, int out_size, void* d_ws, size_t ws_size,
                              hipStream_t stream) {
  const float* feat = (const float*)d_in[0];
  const float* sf   = (const float*)d_in[1];
  const int*   src  = (const int*)d_in[2];
  const int*   dst  = (const int*)d_in[3];
  const int*   n2g  = (const int*)d_in[4];
  const float* W1   = (const float*)d_in[5];
  const float* b1   = (const float*)d_in[6];
  const float* W2   = (const float*)d_in[7];
  const float* b2   = (const float*)d_in[8];
  const float* Wf1  = (const float*)d_in[9];
  const float* bf1  = (const float*)d_in[10];
  const float* g1   = (const float*)d_in[11];
  const float* be1  = (const float*)d_in[12];
  const float* Wf2  = (const float*)d_in[13];
  const float* bf2  = (const float*)d_in[14];
  const float* g2   = (const float*)d_in[15];
  const float* be2  = (const float*)d_in[16];
  const float* Wf3  = (const float*)d_in[17];
  const float* bf3  = (const float*)d_in[18];
  float* out = (float*)d_out;

  char* ws = (char*)d_ws;
  size_t off = 0;
  auto alloc = [&](size_t bytes) -> void* {
    void* p = ws + off;
    off = (off + bytes + 255) & ~(size_t)255;
    return p;
  };
  // zero-init region first (gcnt, hg_sum)
  int*      gcnt     = (int*)alloc(N_GRAPHS * 4);
  float*    hg_sum   = (float*)alloc(N_GRAPHS * D2 * 4);
  size_t zero_bytes = off;
  int*      deg      = (int*)alloc(N_NODES * 4);
  int*      row_off  = (int*)alloc(N_NODES * 4);
  int*      counts   = (int*)alloc((size_t)NBLK1 * NBK * 4);
  int*      offs     = (int*)alloc((size_t)NBLK1 * NBK * 4);
  int*      totals   = (int*)alloc(NBK * 4);
  int*      bin_base = (int*)alloc((NBK + 1) * 4);
  unsigned* packed   = (unsigned*)alloc((size_t)N_EDGES * 4);
  int*      csr      = (int*)alloc((size_t)N_EDGES * 4);
  __half*   p1h      = (__half*)alloc((size_t)N_NODES * D1P * 2);
  __half*   p2h      = (__half*)alloc((size_t)N_NODES * D2P * 2);
  float*    y1       = (float*)alloc((size_t)N_GRAPHS * DF1 * 4);
  float*    y2       = (float*)alloc((size_t)N_GRAPHS * DF2 * 4);
  float*    mu1      = (float*)alloc(DF1 * 4);
  float*    rstd1    = (float*)alloc(DF1 * 4);
  float*    mu2      = (float*)alloc(DF2 * 4);
  float*    rstd2    = (float*)alloc(DF2 * 4);

  hipMemsetAsync(d_ws, 0, zero_bytes, stream);

  k_bcount<<<NBLK1, 256, 0, stream>>>(dst, counts);
  k_bscanA<<<NBK, 64, 0, stream>>>(counts, offs, totals);
  k_bscanB<<<1, NBK, 0, stream>>>(totals, bin_base);
  k_bscatter<<<NBLK1, 256, 0, stream>>>(src, dst, offs, bin_base, packed);
  k_bfine<<<NBK, 256, 0, stream>>>(packed, bin_base, csr, deg, row_off);
  k_gemm1<<<N_NODES / 40, 256, 0, stream>>>(feat, W1, p1h);
  k_agg1<<<N_NODES / 4, 256, 0, stream>>>(p1h, deg, row_off, csr, b1, W2, p2h);
  k_agg2<<<N_NODES / 4, 256, 0, stream>>>(p2h, deg, row_off, csr, b2, n2g, hg_sum, gcnt);
  k_mlp1<<<N_GRAPHS, 128, 0, stream>>>(hg_sum, gcnt, sf, Wf1, bf1, y1);
  k_bnstats<<<DF1, 256, 0, stream>>>(y1, DF1, mu1, rstd1);
  k_mlp2<<<(N_GRAPHS * DF2) / 256, 256, 0, stream>>>(y1, mu1, rstd1, g1, be1, Wf2, bf2, y2);
  k_bnstats<<<DF2, 256, 0, stream>>>(y2, DF2, mu2, rstd2);
  k_mlp3<<<(N_GRAPHS * DOUT) / 256, 256, 0, stream>>>(y2, mu2, rstd2, g2, be2, Wf3, bf3, out);
}

// Round 2
// 405.014 us; speedup vs baseline: 1.4095x; 1.4095x over previous
//
#include <hip/hip_runtime.h>
#include <hip/hip_fp16.h>

#define N_NODES 100000
#define N_EDGES 1600000
#define N_GRAPHS 1024
#define DIM_IN 128
#define D1 100
#define D1P 128            // padded p1 row (halves) -> 256 B, 2 aligned cache lines
#define D2 20
#define D2P 32             // padded p2 row (halves) -> 64 B, 1 cache line
#define DIM_SF 32
#define DF1 128
#define DF2 32
#define DOUT 8
#define EPS 1e-5f

// ---------------- bucket-sort CSR build ----------------
#define NBK 512                 // buckets
#define BW 196                  // nodes per bucket (512*196 = 100352 >= N_NODES)
#define EPB 4096                // edges per block in pass 1
#define NBLK1 ((N_EDGES + EPB - 1) / EPB)   // 391

// pass 1a: per-(block,bucket) histogram. No global atomics.
__global__ void __launch_bounds__(256) k_bcount(const int* __restrict__ dst,
                                                int* __restrict__ counts) {
  __shared__ int hist[NBK];
  int t = threadIdx.x, blk = blockIdx.x;
  for (int i = t; i < NBK; i += 256) hist[i] = 0;
  __syncthreads();
  int base = blk * EPB;
#pragma unroll
  for (int r = 0; r < 16; r++) {
    int e = base + r * 256 + t;
    if (e < N_EDGES) {
      unsigned b = (unsigned)dst[e] / BW;
      atomicAdd(&hist[b], 1);
    }
  }
  __syncthreads();
  for (int i = t; i < NBK; i += 256) counts[blk * NBK + i] = hist[i];
}

// pass 1b: for each bucket, exclusive scan of counts across blocks. 1 wave/bucket.
__global__ void __launch_bounds__(64) k_bscanA(const int* __restrict__ counts,
                                               int* __restrict__ offs,
                                               int* __restrict__ totals) {
  int b = blockIdx.x, l = threadIdx.x;
  int carry = 0;
  for (int chunk = 0; chunk < NBLK1; chunk += 64) {
    int blk = chunk + l;
    int v = (blk < NBLK1) ? counts[blk * NBK + b] : 0;
    int incl = v;
    for (int s = 1; s < 64; s <<= 1) { int x = __shfl_up(incl, s); if (l >= s) incl += x; }
    if (blk < NBLK1) offs[blk * NBK + b] = carry + incl - v;
    carry += __shfl(incl, 63);
  }
  if (l == 0) totals[b] = carry;
}

// pass 1c: exclusive scan of bucket totals -> bucket base offsets (513 entries).
__global__ void __launch_bounds__(512) k_bscanB(const int* __restrict__ totals,
                                                int* __restrict__ bin_base) {
  __shared__ int lds[NBK];
  int t = threadIdx.x;
  int v = totals[t];
  lds[t] = v; __syncthreads();
  for (int s = 1; s < NBK; s <<= 1) {
    int x = (t >= s) ? lds[t - s] : 0;
    __syncthreads();
    lds[t] += x;
    __syncthreads();
  }
  bin_base[t] = lds[t] - v;
  if (t == NBK - 1) bin_base[NBK] = lds[t];
}

// pass 1d: scatter packed (src<<8 | local_dst) into bucket-ordered array.
__global__ void __launch_bounds__(256) k_bscatter(const int* __restrict__ src,
                                                  const int* __restrict__ dst,
                                                  const int* __restrict__ offs,
                                                  const int* __restrict__ bin_base,
                                                  unsigned* __restrict__ packed_out) {
  __shared__ int hist[NBK];
  __shared__ int lbase[NBK];
  __shared__ int gbase[NBK];
  __shared__ int ssum[256];
  __shared__ unsigned sval[EPB];   // 16 KB
  __shared__ int spos[EPB];        // 16 KB
  int t = threadIdx.x, blk = blockIdx.x;
  for (int i = t; i < NBK; i += 256) hist[i] = 0;
  __syncthreads();
  int base = blk * EPB;
  unsigned pk[16]; int bn[16]; int rk[16];
#pragma unroll
  for (int r = 0; r < 16; r++) {
    int e = base + r * 256 + t;
    bn[r] = -1;
    if (e < N_EDGES) {
      int dv = dst[e];
      unsigned b = (unsigned)dv / BW;
      unsigned ld = (unsigned)dv - b * BW;
      bn[r] = (int)b;
      pk[r] = ((unsigned)src[e] << 8) | ld;
      rk[r] = atomicAdd(&hist[b], 1);
    }
  }
  __syncthreads();
  int h0 = hist[2 * t], h1 = hist[2 * t + 1];
  int s = h0 + h1;
  ssum[t] = s; __syncthreads();
  for (int off = 1; off < 256; off <<= 1) {
    int x = (t >= off) ? ssum[t - off] : 0;
    __syncthreads();
    ssum[t] += x;
    __syncthreads();
  }
  int excl = ssum[t] - s;
  lbase[2 * t] = excl;
  lbase[2 * t + 1] = excl + h0;
  gbase[2 * t]     = bin_base[2 * t]     + offs[blk * NBK + 2 * t];
  gbase[2 * t + 1] = bin_base[2 * t + 1] + offs[blk * NBK + 2 * t + 1];
  __syncthreads();
#pragma unroll
  for (int r = 0; r < 16; r++) {
    if (bn[r] >= 0) {
      int li = lbase[bn[r]] + rk[r];
      sval[li] = pk[r];
      spos[li] = gbase[bn[r]] + rk[r];
    }
  }
  __syncthreads();
  int cnt = N_EDGES - base; if (cnt > EPB) cnt = EPB;
  for (int i = t; i < cnt; i += 256) packed_out[spos[i]] = sval[i];
}

// pass 2: one block per bucket. Sort within bucket in LDS, emit exact CSR.
__global__ void __launch_bounds__(256) k_bfine(const unsigned* __restrict__ packed_in,
                                               const int* __restrict__ bin_base,
                                               int* __restrict__ csr,
                                               int* __restrict__ deg,
                                               int* __restrict__ row_off) {
  __shared__ unsigned sval[EPB];   // 16 KB
  __shared__ int scsr[EPB];        // 16 KB
  __shared__ int hist[256];
  __shared__ int soff[256];
  __shared__ int cur[256];
  int b = blockIdx.x, t = threadIdx.x;
  int start = bin_base[b];
  int cnt = bin_base[b + 1] - start;
  if (cnt > EPB) cnt = EPB;
  hist[t] = 0;
  __syncthreads();
  for (int i = t; i < cnt; i += 256) {
    unsigned v = packed_in[start + i];
    sval[i] = v;
    atomicAdd(&hist[v & 255u], 1);
  }
  __syncthreads();
  int h = hist[t];
  soff[t] = h; __syncthreads();
  for (int off = 1; off < 256; off <<= 1) {
    int x = (t >= off) ? soff[t - off] : 0;
    __syncthreads();
    soff[t] += x;
    __syncthreads();
  }
  int excl = soff[t] - h;
  cur[t] = excl;
  int n = b * BW + t;
  if (t < BW && n < N_NODES) { deg[n] = h; row_off[n] = start + excl; }
  __syncthreads();
  for (int i = t; i < cnt; i += 256) {
    unsigned v = sval[i];
    int pos = atomicAdd(&cur[v & 255u], 1);
    scsr[pos] = (int)(v >> 8);
  }
  __syncthreads();
  for (int i = t; i < cnt; i += 256) csr[start + i] = scsr[i];
}

// ---------------- graph offsets: g_off[g] = lower_bound(n2g, g) ----------------
__global__ void __launch_bounds__(256) k_goff(const int* __restrict__ n2g,
                                              int* __restrict__ g_off) {
  int g = blockIdx.x * 256 + threadIdx.x;
  if (g > N_GRAPHS) return;
  if (g == N_GRAPHS) { g_off[g] = N_NODES; return; }
  int lo = 0, hi = N_NODES;
  while (lo < hi) {
    int mid = (lo + hi) >> 1;
    if (n2g[mid] < g) lo = mid + 1; else hi = mid;
  }
  g_off[g] = lo;
}

// ---------------- p1 = fp16(feat @ W1), rows padded to D1P=128 halves ----------------
// Pad columns 100..127 are left uninitialized; every consumer discards them.
__global__ void __launch_bounds__(256) k_gemm1(const float* __restrict__ feat,
                                               const float* __restrict__ W1,
                                               __half* __restrict__ p1h) {
  __shared__ float w1s[DIM_IN * D1];   // 51.2 KB
  int t = threadIdx.x;
  for (int i = t; i < DIM_IN * D1; i += 256) w1s[i] = W1[i];
  __syncthreads();
  if (t >= 250) return;
  int q = t % 25, ng = t / 25;
  int n0 = blockIdx.x * 40 + ng * 4;   // grid 2500 -> exactly 100000 nodes
  int c0 = q * 4;
  float acc[4][4] = {{0.f}};
  const float* f0 = feat + (size_t)n0 * DIM_IN;
  for (int k = 0; k < DIM_IN; k += 4) {
    float4 w0 = *(const float4*)&w1s[(k + 0) * D1 + c0];
    float4 w1 = *(const float4*)&w1s[(k + 1) * D1 + c0];
    float4 w2 = *(const float4*)&w1s[(k + 2) * D1 + c0];
    float4 w3 = *(const float4*)&w1s[(k + 3) * D1 + c0];
#pragma unroll
    for (int j = 0; j < 4; j++) {
      float4 f = *(const float4*)(f0 + j * DIM_IN + k);
      acc[j][0] += f.x * w0.x + f.y * w1.x + f.z * w2.x + f.w * w3.x;
      acc[j][1] += f.x * w0.y + f.y * w1.y + f.z * w2.y + f.w * w3.y;
      acc[j][2] += f.x * w0.z + f.y * w1.z + f.z * w2.z + f.w * w3.z;
      acc[j][3] += f.x * w0.w + f.y * w1.w + f.z * w2.w + f.w * w3.w;
    }
  }
#pragma unroll
  for (int j = 0; j < 4; j++) {
    __half2* d2 = (__half2*)(p1h + (size_t)(n0 + j) * D1P + c0);
    d2[0] = __floats2half2_rn(acc[j][0], acc[j][1]);
    d2[1] = __floats2half2_rn(acc[j][2], acc[j][3]);
  }
}

__device__ __forceinline__ void acc8(int4 raw, float4& A, float4& B) {
  const __half2* h = (const __half2*)&raw;
  float2 f0 = __half22float2(h[0]);
  float2 f1 = __half22float2(h[1]);
  float2 f2 = __half22float2(h[2]);
  float2 f3 = __half22float2(h[3]);
  A.x += f0.x; A.y += f0.y; A.z += f1.x; A.w += f1.y;
  B.x += f2.x; B.y += f2.y; B.z += f3.x; B.w += f3.y;
}

// ---------- agg1: wave-per-node gather (4 edges per dwordx4 round) + b1 + relu + GEMM2 ----------
__global__ void __launch_bounds__(256) k_agg1(const __half* __restrict__ p1h,
                                              const int* __restrict__ deg,
                                              const int* __restrict__ row_off,
                                              const int* __restrict__ csr,
                                              const float* __restrict__ b1,
                                              const float* __restrict__ W2,
                                              __half* __restrict__ p2h) {
  __shared__ float w2s[D1 * D2];
  __shared__ float b1s[D1];
  __shared__ float hbuf[4][104];
  int t = threadIdx.x;
  for (int i = t; i < D1 * D2; i += 256) w2s[i] = W2[i];
  if (t < D1) b1s[t] = b1[t];
  __syncthreads();
  int w = t >> 6, lane = t & 63;
  int n = blockIdx.x * 4 + w;
  int g = lane >> 4, o = lane & 15;         // 4 edge-slots x 16B-slots; lane covers ch 8o..8o+7
  int d = deg[n], ro = row_off[n];
  float4 A = {0.f, 0.f, 0.f, 0.f}, B = {0.f, 0.f, 0.f, 0.f};
  const size_t obyte = (size_t)(o * 8);     // halves offset within row
  if (d > 0) {
    for (int base = 0; base < d; base += 64) {
      int m = d - base; if (m > 64) m = 64;
      int sv = (lane < m) ? csr[ro + base + lane] : 0;
      int nr = m >> 2;
      int r = 0;
      for (; r + 1 < nr; r += 2) {          // 8 edges in flight
        int sA = __shfl(sv, r * 4 + g);
        int sB = __shfl(sv, r * 4 + 4 + g);
        int4 ra = *(const int4*)(p1h + (size_t)sA * D1P + obyte);
        int4 rb = *(const int4*)(p1h + (size_t)sB * D1P + obyte);
        acc8(ra, A, B);
        acc8(rb, A, B);
      }
      if (r < nr) {
        int sA = __shfl(sv, r * 4 + g);
        int4 ra = *(const int4*)(p1h + (size_t)sA * D1P + obyte);
        acc8(ra, A, B);
      }
      int rem = m & 3;
      int sT = __shfl(sv, nr * 4 + g);      // hoisted out of divergent branch
      if (rem && g < rem) {
        int4 ra = *(const int4*)(p1h + (size_t)sT * D1P + obyte);
        acc8(ra, A, B);
      }
    }
  } else {
    if (g == 0) {                           // deg==0: agg = own p1 row
      int4 ra = *(const int4*)(p1h + (size_t)n * D1P + obyte);
      acc8(ra, A, B);
    }
  }
  // reduce the 4 edge-groups: lanes {o, o+16, o+32, o+48} -> lane o
  float v[8] = {A.x, A.y, A.z, A.w, B.x, B.y, B.z, B.w};
#pragma unroll
  for (int j = 0; j < 8; j++) {
    v[j] += __shfl_down(v[j], 32);
    v[j] += __shfl_down(v[j], 16);
  }
  if (lane < 13) {
    float inv = (d > 0) ? 1.0f / (float)d : 1.0f;
#pragma unroll
    for (int j = 0; j < 8; j++) {
      int ch = 8 * lane + j;
      if (ch < D1) hbuf[w][ch] = fmaxf(v[j] * inv + b1s[ch], 0.f);
    }
  }
  __syncthreads();
  // GEMM2: 3 lane-groups of 20 split the 100-dot; 2-shuffle reduce.
  int p = lane / 20;                        // 0..3 (p==3 idle)
  int j20 = lane - p * 20;
  int cbeg = p * 33 + (p > 0);              // 0,34,67,100
  int cend = (p + 1) * 33 + 1;              // 34,67,100,133
  if (cend > D1) cend = D1;
  float acc = 0.f;
  for (int c = cbeg; c < cend; c++) acc += hbuf[w][c] * w2s[c * D2 + j20];
  float t1 = __shfl_down(acc, 20);
  float t2 = __shfl_down(acc, 40);
  acc += t1 + t2;
  if (lane < D2)       p2h[(size_t)n * D2P + lane] = __float2half_rn(acc);
  else if (lane < D2P) p2h[(size_t)n * D2P + lane] = __float2half_rn(0.f);
}

// ---------- agg2: block-per-graph, thread-per-(node,channel), LDS reduce, no global atomics ----------
__global__ void __launch_bounds__(512) k_agg2(const __half* __restrict__ p2h,
                                              const int* __restrict__ deg,
                                              const int* __restrict__ row_off,
                                              const int* __restrict__ csr,
                                              const float* __restrict__ b2,
                                              const int* __restrict__ g_off,
                                              float* __restrict__ hg) {
  __shared__ float ssum[D2];
  __shared__ float b2s[D2];
  int g = blockIdx.x, t = threadIdx.x;
  if (t < D2) { ssum[t] = 0.f; b2s[t] = b2[t]; }
  __syncthreads();
  int n_lo = g_off[g], n_hi = g_off[g + 1];
  int total = (n_hi - n_lo) * D2;
  for (int idx = t; idx < total; idx += 512) {
    int n = n_lo + idx / D2;
    int c = idx % D2;
    int d = deg[n], ro = row_off[n];
    float acc;
    if (d > 0) {
      float a0 = 0.f, a1 = 0.f, a2 = 0.f, a3 = 0.f;
      int e = 0;
      for (; e + 3 < d; e += 4) {
        int s0 = csr[ro + e],     s1 = csr[ro + e + 1];
        int s2 = csr[ro + e + 2], s3 = csr[ro + e + 3];
        a0 += __half2float(p2h[(size_t)s0 * D2P + c]);
        a1 += __half2float(p2h[(size_t)s1 * D2P + c]);
        a2 += __half2float(p2h[(size_t)s2 * D2P + c]);
        a3 += __half2float(p2h[(size_t)s3 * D2P + c]);
      }
      for (; e < d; e++) a0 += __half2float(p2h[(size_t)csr[ro + e] * D2P + c]);
      acc = ((a0 + a1) + (a2 + a3)) / (float)d;
    } else {
      acc = __half2float(p2h[(size_t)n * D2P + c]);
    }
    float val = fmaxf(acc + b2s[c], 0.f);
    atomicAdd(&ssum[c], val);               // LDS atomic, <=3-way conflict per wave
  }
  __syncthreads();
  if (t < D2) {
    int cnt = n_hi - n_lo;
    float inv = (cnt > 0) ? 1.0f / (float)cnt : 0.f;
    hg[g * D2 + t] = ssum[t] * inv;         // per-graph mean, written once, no atomics
  }
}

// ---------- head ----------
__global__ void __launch_bounds__(128) k_mlp1(const float* __restrict__ hg,
                                              const float* __restrict__ sf,
                                              const float* __restrict__ Wf1,
                                              const float* __restrict__ bf1,
                                              float* __restrict__ y1) {
  __shared__ float prod[D2 * DIM_SF];
  __shared__ float hgl[D2], sfl[DIM_SF];
  int g = blockIdx.x, t = threadIdx.x;
  if (t < D2) hgl[t] = hg[g * D2 + t];
  if (t < DIM_SF) sfl[t] = sf[g * DIM_SF + t];
  __syncthreads();
  for (int i = t; i < D2 * DIM_SF; i += 128) prod[i] = hgl[i >> 5] * sfl[i & 31];
  __syncthreads();
  float acc = bf1[t];
#pragma unroll 4
  for (int k = 0; k < D2 * DIM_SF; k++) acc += prod[k] * Wf1[k * DF1 + t];
  y1[g * DF1 + t] = acc;
}

__global__ void k_bnstats(const float* __restrict__ x, int ld,
                          float* __restrict__ mu, float* __restrict__ rstd) {
  __shared__ float ssum[256], ssq[256];
  int c = blockIdx.x, t = threadIdx.x;
  float s = 0.f, q = 0.f;
  for (int r = t; r < N_GRAPHS; r += 256) { float v = x[r * ld + c]; s += v; q += v * v; }
  ssum[t] = s; ssq[t] = q; __syncthreads();
  for (int off = 128; off > 0; off >>= 1) {
    if (t < off) { ssum[t] += ssum[t + off]; ssq[t] += ssq[t + off]; }
    __syncthreads();
  }
  if (t == 0) {
    float m = ssum[0] / (float)N_GRAPHS;
    float var = ssq[0] / (float)N_GRAPHS - m * m;
    mu[c] = m;
    rstd[c] = rsqrtf(var + EPS);
  }
}

__global__ void k_mlp2(const float* __restrict__ y1, const float* __restrict__ mu1,
                       const float* __restrict__ rstd1, const float* __restrict__ g1,
                       const float* __restrict__ be1, const float* __restrict__ Wf2,
                       const float* __restrict__ bf2, float* __restrict__ y2) {
  int idx = blockIdx.x * 256 + threadIdx.x;
  int g = idx >> 5, o = idx & 31;
  float acc = bf2[o];
  for (int k = 0; k < DF1; k++) {
    float x = (y1[g * DF1 + k] - mu1[k]) * rstd1[k] * g1[k] + be1[k];
    x = fmaxf(x, 0.f);
    acc += x * Wf2[k * DF2 + o];
  }
  y2[g * DF2 + o] = acc;
}

__global__ void k_mlp3(const float* __restrict__ y2, const float* __restrict__ mu2,
                       const float* __restrict__ rstd2, const float* __restrict__ g2,
                       const float* __restrict__ be2, const float* __restrict__ Wf3,
                       const float* __restrict__ bf3, float* __restrict__ out) {
  int idx = blockIdx.x * 256 + threadIdx.x;
  int g = idx >> 3, o = idx & 7;
  float acc = bf3[o];
  for (int k = 0; k < DF2; k++) {
    float x = (y2[g * DF2 + k] - mu2[k]) * rstd2[k] * g2[k] + be2[k];
    x = fmaxf(x, 0.f);
    acc += x * Wf3[k * DOUT + o];
  }
  out[g * DOUT + o] = acc;
}

extern "C" void kernel_launch(void* const* d_in, const int* in_sizes, int n_in,
                              void* d_out, int out_size, void* d_ws, size_t ws_size,
                              hipStream_t stream) {
  const float* feat = (const float*)d_in[0];
  const float* sf   = (const float*)d_in[1];
  const int*   src  = (const int*)d_in[2];
  const int*   dst  = (const int*)d_in[3];
  const int*   n2g  = (const int*)d_in[4];
  const float* W1   = (const float*)d_in[5];
  const float* b1   = (const float*)d_in[6];
  const float* W2   = (const float*)d_in[7];
  const float* b2   = (const float*)d_in[8];
  const float* Wf1  = (const float*)d_in[9];
  const float* bf1  = (const float*)d_in[10];
  const float* g1   = (const float*)d_in[11];
  const float* be1  = (const float*)d_in[12];
  const float* Wf2  = (const float*)d_in[13];
  const float* bf2  = (const float*)d_in[14];
  const float* g2   = (const float*)d_in[15];
  const float* be2  = (const float*)d_in[16];
  const float* Wf3  = (const float*)d_in[17];
  const float* bf3  = (const float*)d_in[18];
  float* out = (float*)d_out;

  char* ws = (char*)d_ws;
  size_t off = 0;
  auto alloc = [&](size_t bytes) -> void* {
    void* p = ws + off;
    off = (off + bytes + 255) & ~(size_t)255;
    return p;
  };
  int*      g_offs   = (int*)alloc((N_GRAPHS + 1) * 4);
  float*    hg       = (float*)alloc(N_GRAPHS * D2 * 4);
  int*      deg      = (int*)alloc(N_NODES * 4);
  int*      row_off  = (int*)alloc(N_NODES * 4);
  int*      counts   = (int*)alloc((size_t)NBLK1 * NBK * 4);
  int*      offs     = (int*)alloc((size_t)NBLK1 * NBK * 4);
  int*      totals   = (int*)alloc(NBK * 4);
  int*      bin_base = (int*)alloc((NBK + 1) * 4);
  unsigned* packed   = (unsigned*)alloc((size_t)N_EDGES * 4);
  int*      csr      = (int*)alloc((size_t)N_EDGES * 4);
  __half*   p1h      = (__half*)alloc((size_t)N_NODES * D1P * 2);
  __half*   p2h      = (__half*)alloc((size_t)N_NODES * D2P * 2);
  float*    y1       = (float*)alloc((size_t)N_GRAPHS * DF1 * 4);
  float*    y2       = (float*)alloc((size_t)N_GRAPHS * DF2 * 4);
  float*    mu1      = (float*)alloc(DF1 * 4);
  float*    rstd1    = (float*)alloc(DF1 * 4);
  float*    mu2      = (float*)alloc(DF2 * 4);
  float*    rstd2    = (float*)alloc(DF2 * 4);

  k_goff<<<(N_GRAPHS + 1 + 255) / 256, 256, 0, stream>>>(n2g, g_offs);
  k_bcount<<<NBLK1, 256, 0, stream>>>(dst, counts);
  k_bscanA<<<NBK, 64, 0, stream>>>(counts, offs, totals);
  k_bscanB<<<1, NBK, 0, stream>>>(totals, bin_base);
  k_bscatter<<<NBLK1, 256, 0, stream>>>(src, dst, offs, bin_base, packed);
  k_bfine<<<NBK, 256, 0, stream>>>(packed, bin_base, csr, deg, row_off);
  k_gemm1<<<N_NODES / 40, 256, 0, stream>>>(feat, W1, p1h);
  k_agg1<<<N_NODES / 4, 256, 0, stream>>>(p1h, deg, row_off, csr, b1, W2, p2h);
  k_agg2<<<N_GRAPHS, 512, 0, stream>>>(p2h, deg, row_off, csr, b2, g_offs, hg);
  k_mlp1<<<N_GRAPHS, 128, 0, stream>>>(hg, sf, Wf1, bf1, y1);
  k_bnstats<<<DF1, 256, 0, stream>>>(y1, DF1, mu1, rstd1);
  k_mlp2<<<(N_GRAPHS * DF2) / 256, 256, 0, stream>>>(y1, mu1, rstd1, g1, be1, Wf2, bf2, y2);
  k_bnstats<<<DF2, 256, 0, stream>>>(y2, DF2, mu2, rstd2);
  k_mlp3<<<(N_GRAPHS * DOUT) / 256, 256, 0, stream>>>(y2, mu2, rstd2, g2, be2, Wf3, bf3, out);
}

// Round 3
// 400.860 us; speedup vs baseline: 1.4241x; 1.0104x over previous
//
#include <hip/hip_runtime.h>
#include <hip/hip_fp16.h>

#define N_NODES 100000
#define N_EDGES 1600000
#define N_GRAPHS 1024
#define DIM_IN 128
#define D1 100
#define D1P 128            // padded p1 row (halves) -> 256 B, 2 aligned cache lines
#define D2 20
#define D2P 32             // padded p2 row (halves) -> 64 B, 1 cache line
#define DIM_SF 32
#define DF1 128
#define DF2 32
#define DOUT 8
#define EPS 1e-5f

typedef _Float16 hh2 __attribute__((ext_vector_type(2)));

// one f32 accumulate of each half in a packed half2, via v_dot2_f32_f16 (exact)
__device__ __forceinline__ void fdacc(unsigned u, float& lo, float& hi) {
  const hh2 MLO = {(_Float16)1.0f, (_Float16)0.0f};
  const hh2 MHI = {(_Float16)0.0f, (_Float16)1.0f};
  hh2 h = __builtin_bit_cast(hh2, u);
  lo = __builtin_amdgcn_fdot2(h, MLO, lo, false);
  hi = __builtin_amdgcn_fdot2(h, MHI, hi, false);
}

__device__ __forceinline__ unsigned pkadd(unsigned a, unsigned b) {
  __half2 x = __builtin_bit_cast(__half2, a);
  __half2 y = __builtin_bit_cast(__half2, b);
  return __builtin_bit_cast(unsigned, __hadd2(x, y));
}

// ---------------- bucket-sort CSR build ----------------
#define NBK 512                 // buckets
#define BW 196                  // nodes per bucket (512*196 = 100352 >= N_NODES)
#define EPB 4096                // edges per block in pass 1
#define NBLK1 ((N_EDGES + EPB - 1) / EPB)   // 391

// pass 1a: per-(block,bucket) histogram. No global atomics.
__global__ void __launch_bounds__(256) k_bcount(const int* __restrict__ dst,
                                                int* __restrict__ counts) {
  __shared__ int hist[NBK];
  int t = threadIdx.x, blk = blockIdx.x;
  for (int i = t; i < NBK; i += 256) hist[i] = 0;
  __syncthreads();
  int base = blk * EPB;
#pragma unroll
  for (int r = 0; r < 16; r++) {
    int e = base + r * 256 + t;
    if (e < N_EDGES) {
      unsigned b = (unsigned)dst[e] / BW;
      atomicAdd(&hist[b], 1);
    }
  }
  __syncthreads();
  for (int i = t; i < NBK; i += 256) counts[blk * NBK + i] = hist[i];
}

// pass 1b: for each bucket, exclusive scan of counts across blocks. 1 wave/bucket.
__global__ void __launch_bounds__(64) k_bscanA(const int* __restrict__ counts,
                                               int* __restrict__ offs,
                                               int* __restrict__ totals) {
  int b = blockIdx.x, l = threadIdx.x;
  int carry = 0;
  for (int chunk = 0; chunk < NBLK1; chunk += 64) {
    int blk = chunk + l;
    int v = (blk < NBLK1) ? counts[blk * NBK + b] : 0;
    int incl = v;
    for (int s = 1; s < 64; s <<= 1) { int x = __shfl_up(incl, s); if (l >= s) incl += x; }
    if (blk < NBLK1) offs[blk * NBK + b] = carry + incl - v;
    carry += __shfl(incl, 63);
  }
  if (l == 0) totals[b] = carry;
}

// pass 1c: exclusive scan of bucket totals -> bucket base offsets (513 entries).
__global__ void __launch_bounds__(512) k_bscanB(const int* __restrict__ totals,
                                                int* __restrict__ bin_base) {
  __shared__ int lds[NBK];
  int t = threadIdx.x;
  int v = totals[t];
  lds[t] = v; __syncthreads();
  for (int s = 1; s < NBK; s <<= 1) {
    int x = (t >= s) ? lds[t - s] : 0;
    __syncthreads();
    lds[t] += x;
    __syncthreads();
  }
  bin_base[t] = lds[t] - v;
  if (t == NBK - 1) bin_base[NBK] = lds[t];
}

// pass 1d: scatter packed (src<<8 | local_dst) into bucket-ordered array.
__global__ void __launch_bounds__(256) k_bscatter(const int* __restrict__ src,
                                                  const int* __restrict__ dst,
                                                  const int* __restrict__ offs,
                                                  const int* __restrict__ bin_base,
                                                  unsigned* __restrict__ packed_out) {
  __shared__ int hist[NBK];
  __shared__ int lbase[NBK];
  __shared__ int gbase[NBK];
  __shared__ int ssum[256];
  __shared__ unsigned sval[EPB];   // 16 KB
  __shared__ int spos[EPB];        // 16 KB
  int t = threadIdx.x, blk = blockIdx.x;
  for (int i = t; i < NBK; i += 256) hist[i] = 0;
  __syncthreads();
  int base = blk * EPB;
  unsigned pk[16]; int bn[16]; int rk[16];
#pragma unroll
  for (int r = 0; r < 16; r++) {
    int e = base + r * 256 + t;
    bn[r] = -1;
    if (e < N_EDGES) {
      int dv = dst[e];
      unsigned b = (unsigned)dv / BW;
      unsigned ld = (unsigned)dv - b * BW;
      bn[r] = (int)b;
      pk[r] = ((unsigned)src[e] << 8) | ld;
      rk[r] = atomicAdd(&hist[b], 1);
    }
  }
  __syncthreads();
  int h0 = hist[2 * t], h1 = hist[2 * t + 1];
  int s = h0 + h1;
  ssum[t] = s; __syncthreads();
  for (int off = 1; off < 256; off <<= 1) {
    int x = (t >= off) ? ssum[t - off] : 0;
    __syncthreads();
    ssum[t] += x;
    __syncthreads();
  }
  int excl = ssum[t] - s;
  lbase[2 * t] = excl;
  lbase[2 * t + 1] = excl + h0;
  gbase[2 * t]     = bin_base[2 * t]     + offs[blk * NBK + 2 * t];
  gbase[2 * t + 1] = bin_base[2 * t + 1] + offs[blk * NBK + 2 * t + 1];
  __syncthreads();
#pragma unroll
  for (int r = 0; r < 16; r++) {
    if (bn[r] >= 0) {
      int li = lbase[bn[r]] + rk[r];
      sval[li] = pk[r];
      spos[li] = gbase[bn[r]] + rk[r];
    }
  }
  __syncthreads();
  int cnt = N_EDGES - base; if (cnt > EPB) cnt = EPB;
  for (int i = t; i < cnt; i += 256) packed_out[spos[i]] = sval[i];
}

// pass 2: one block per bucket. Sort within bucket in LDS, emit exact CSR.
__global__ void __launch_bounds__(256) k_bfine(const unsigned* __restrict__ packed_in,
                                               const int* __restrict__ bin_base,
                                               int* __restrict__ csr,
                                               int* __restrict__ deg,
                                               int* __restrict__ row_off) {
  __shared__ unsigned sval[EPB];   // 16 KB
  __shared__ int scsr[EPB];        // 16 KB
  __shared__ int hist[256];
  __shared__ int soff[256];
  __shared__ int cur[256];
  int b = blockIdx.x, t = threadIdx.x;
  int start = bin_base[b];
  int cnt = bin_base[b + 1] - start;
  if (cnt > EPB) cnt = EPB;
  hist[t] = 0;
  __syncthreads();
  for (int i = t; i < cnt; i += 256) {
    unsigned v = packed_in[start + i];
    sval[i] = v;
    atomicAdd(&hist[v & 255u], 1);
  }
  __syncthreads();
  int h = hist[t];
  soff[t] = h; __syncthreads();
  for (int off = 1; off < 256; off <<= 1) {
    int x = (t >= off) ? soff[t - off] : 0;
    __syncthreads();
    soff[t] += x;
    __syncthreads();
  }
  int excl = soff[t] - h;
  cur[t] = excl;
  int n = b * BW + t;
  if (t < BW && n < N_NODES) { deg[n] = h; row_off[n] = start + excl; }
  __syncthreads();
  for (int i = t; i < cnt; i += 256) {
    unsigned v = sval[i];
    int pos = atomicAdd(&cur[v & 255u], 1);
    scsr[pos] = (int)(v >> 8);
  }
  __syncthreads();
  for (int i = t; i < cnt; i += 256) csr[start + i] = scsr[i];
}

// ---------------- graph offsets: g_off[g] = lower_bound(n2g, g) ----------------
__global__ void __launch_bounds__(256) k_goff(const int* __restrict__ n2g,
                                              int* __restrict__ g_off) {
  int g = blockIdx.x * 256 + threadIdx.x;
  if (g > N_GRAPHS) return;
  if (g == N_GRAPHS) { g_off[g] = N_NODES; return; }
  int lo = 0, hi = N_NODES;
  while (lo < hi) {
    int mid = (lo + hi) >> 1;
    if (n2g[mid] < g) lo = mid + 1; else hi = mid;
  }
  g_off[g] = lo;
}

// ---------------- p1 = fp16(feat @ W1), rows padded to D1P=128 halves ----------------
// Pad columns 100..127 are left uninitialized; every consumer discards them.
__global__ void __launch_bounds__(256) k_gemm1(const float* __restrict__ feat,
                                               const float* __restrict__ W1,
                                               __half* __restrict__ p1h) {
  __shared__ float w1s[DIM_IN * D1];   // 51.2 KB
  int t = threadIdx.x;
  for (int i = t; i < DIM_IN * D1; i += 256) w1s[i] = W1[i];
  __syncthreads();
  if (t >= 250) return;
  int q = t % 25, ng = t / 25;
  int n0 = blockIdx.x * 40 + ng * 4;   // grid 2500 -> exactly 100000 nodes
  int c0 = q * 4;
  float acc[4][4] = {{0.f}};
  const float* f0 = feat + (size_t)n0 * DIM_IN;
  for (int k = 0; k < DIM_IN; k += 4) {
    float4 w0 = *(const float4*)&w1s[(k + 0) * D1 + c0];
    float4 w1 = *(const float4*)&w1s[(k + 1) * D1 + c0];
    float4 w2 = *(const float4*)&w1s[(k + 2) * D1 + c0];
    float4 w3 = *(const float4*)&w1s[(k + 3) * D1 + c0];
#pragma unroll
    for (int j = 0; j < 4; j++) {
      float4 f = *(const float4*)(f0 + j * DIM_IN + k);
      acc[j][0] += f.x * w0.x + f.y * w1.x + f.z * w2.x + f.w * w3.x;
      acc[j][1] += f.x * w0.y + f.y * w1.y + f.z * w2.y + f.w * w3.y;
      acc[j][2] += f.x * w0.z + f.y * w1.z + f.z * w2.z + f.w * w3.z;
      acc[j][3] += f.x * w0.w + f.y * w1.w + f.z * w2.w + f.w * w3.w;
    }
  }
#pragma unroll
  for (int j = 0; j < 4; j++) {
    __half2* d2 = (__half2*)(p1h + (size_t)(n0 + j) * D1P + c0);
    d2[0] = __floats2half2_rn(acc[j][0], acc[j][1]);
    d2[1] = __floats2half2_rn(acc[j][2], acc[j][3]);
  }
}

// accumulate 8 packed halves into 8 f32 accumulators via fdot2
__device__ __forceinline__ void acc8d(uint4 r, float4& A, float4& B) {
  fdacc(r.x, A.x, A.y);
  fdacc(r.y, A.z, A.w);
  fdacc(r.z, B.x, B.y);
  fdacc(r.w, B.z, B.w);
}

// ---------- agg1: wave-per-node gather (4 edges per dwordx4 round) + b1 + relu + GEMM2 ----------
__global__ void __launch_bounds__(256) k_agg1(const __half* __restrict__ p1h,
                                              const int* __restrict__ deg,
                                              const int* __restrict__ row_off,
                                              const int* __restrict__ csr,
                                              const float* __restrict__ b1,
                                              const float* __restrict__ W2,
                                              __half* __restrict__ p2h) {
  __shared__ float w2s[D1 * D2];
  __shared__ float b1s[D1];
  __shared__ float hbuf[4][104];
  int t = threadIdx.x;
  for (int i = t; i < D1 * D2; i += 256) w2s[i] = W2[i];
  if (t < D1) b1s[t] = b1[t];
  __syncthreads();
  int w = t >> 6, lane = t & 63;
  int n = blockIdx.x * 4 + w;
  int g = lane >> 4, o = lane & 15;         // 4 edge-slots x 16B-slots; lane covers ch 8o..8o+7
  int d = deg[n], ro = row_off[n];
  float4 A = {0.f, 0.f, 0.f, 0.f}, B = {0.f, 0.f, 0.f, 0.f};
  const size_t oh = (size_t)(o * 8);        // halves offset within row
  if (d > 0) {
    for (int base = 0; base < d; base += 64) {
      int m = d - base; if (m > 64) m = 64;
      int sv = (lane < m) ? csr[ro + base + lane] : 0;
      int nr = m >> 2;
      int r = 0;
      for (; r + 1 < nr; r += 2) {          // 8 edges in flight
        int sA = __shfl(sv, r * 4 + g);
        int sB = __shfl(sv, r * 4 + 4 + g);
        uint4 ra = *(const uint4*)(p1h + (size_t)sA * D1P + oh);
        uint4 rb = *(const uint4*)(p1h + (size_t)sB * D1P + oh);
        uint4 rc;
        rc.x = pkadd(ra.x, rb.x); rc.y = pkadd(ra.y, rb.y);
        rc.z = pkadd(ra.z, rb.z); rc.w = pkadd(ra.w, rb.w);
        acc8d(rc, A, B);
      }
      if (r < nr) {
        int sA = __shfl(sv, r * 4 + g);
        uint4 ra = *(const uint4*)(p1h + (size_t)sA * D1P + oh);
        acc8d(ra, A, B);
      }
      int rem = m & 3;
      int sT = __shfl(sv, nr * 4 + g);      // hoisted out of divergent branch
      if (rem && g < rem) {
        uint4 ra = *(const uint4*)(p1h + (size_t)sT * D1P + oh);
        acc8d(ra, A, B);
      }
    }
  } else {
    if (g == 0) {                           // deg==0: agg = own p1 row
      uint4 ra = *(const uint4*)(p1h + (size_t)n * D1P + oh);
      acc8d(ra, A, B);
    }
  }
  // reduce the 4 edge-groups: lanes {o, o+16, o+32, o+48} -> lane o
  float v[8] = {A.x, A.y, A.z, A.w, B.x, B.y, B.z, B.w};
#pragma unroll
  for (int j = 0; j < 8; j++) {
    v[j] += __shfl_down(v[j], 32);
    v[j] += __shfl_down(v[j], 16);
  }
  if (lane < 13) {
    float inv = (d > 0) ? 1.0f / (float)d : 1.0f;
#pragma unroll
    for (int j = 0; j < 8; j++) {
      int ch = 8 * lane + j;
      if (ch < D1) hbuf[w][ch] = fmaxf(v[j] * inv + b1s[ch], 0.f);
    }
  }
  __syncthreads();
  // GEMM2: 3 lane-groups of 20 split the 100-dot at {0,33,66}.
  // Bank shifts of the three 20-lane w2s runs: {0,+20,+8} -> no triple overlap,
  // max 2-way aliasing (free on 32-bank LDS with wave64).
  int p = lane / 20;                        // 0..3 (p==3 idle)
  int j20 = lane - p * 20;
  int cbeg = (p == 0) ? 0 : (p == 1) ? 33 : 66;
  int cend = (p == 0) ? 33 : (p == 1) ? 66 : 100;
  if (p >= 3) { cbeg = 0; cend = 0; }
  float acc = 0.f;
  for (int c = cbeg; c < cend; c++) acc += hbuf[w][c] * w2s[c * D2 + j20];
  float t1 = __shfl_down(acc, 20);
  float t2 = __shfl_down(acc, 40);
  acc += t1 + t2;
  if (lane < D2)       p2h[(size_t)n * D2P + lane] = __float2half_rn(acc);
  else if (lane < D2P) p2h[(size_t)n * D2P + lane] = __float2half_rn(0.f);
}

// ---------- agg2: block-per-graph, thread-per-(node,channel-pair), LDS reduce ----------
__global__ void __launch_bounds__(512) k_agg2(const __half* __restrict__ p2h,
                                              const int* __restrict__ deg,
                                              const int* __restrict__ row_off,
                                              const int* __restrict__ csr,
                                              const float* __restrict__ b2,
                                              const int* __restrict__ g_off,
                                              float* __restrict__ hg) {
  __shared__ float ssum[D2];
  __shared__ float b2s[D2];
  int g = blockIdx.x, t = threadIdx.x;
  if (t < D2) { ssum[t] = 0.f; b2s[t] = b2[t]; }
  __syncthreads();
  const unsigned* pu = (const unsigned*)p2h;   // 16 dwords per row
  int n_lo = g_off[g], n_hi = g_off[g + 1];
  int total = (n_hi - n_lo) * 10;
  for (int idx = t; idx < total; idx += 512) {
    int n = n_lo + idx / 10;
    int c2 = idx % 10;                      // channels 2*c2, 2*c2+1
    int d = deg[n], ro = row_off[n];
    float lo, hi;
    if (d > 0) {
      float l0 = 0.f, h0 = 0.f, l1 = 0.f, h1 = 0.f;
      int e = 0;
      for (; e + 3 < d; e += 4) {
        unsigned u0 = pu[(size_t)csr[ro + e]     * 16 + c2];
        unsigned u1 = pu[(size_t)csr[ro + e + 1] * 16 + c2];
        unsigned u2 = pu[(size_t)csr[ro + e + 2] * 16 + c2];
        unsigned u3 = pu[(size_t)csr[ro + e + 3] * 16 + c2];
        fdacc(u0, l0, h0); fdacc(u1, l1, h1);
        fdacc(u2, l0, h0); fdacc(u3, l1, h1);
      }
      for (; e < d; e++) {
        unsigned u = pu[(size_t)csr[ro + e] * 16 + c2];
        fdacc(u, l0, h0);
      }
      float inv = 1.0f / (float)d;
      lo = (l0 + l1) * inv; hi = (h0 + h1) * inv;
    } else {
      lo = 0.f; hi = 0.f;
      fdacc(pu[(size_t)n * 16 + c2], lo, hi);
    }
    atomicAdd(&ssum[2 * c2],     fmaxf(lo + b2s[2 * c2],     0.f));
    atomicAdd(&ssum[2 * c2 + 1], fmaxf(hi + b2s[2 * c2 + 1], 0.f));
  }
  __syncthreads();
  if (t < D2) {
    int cnt = n_hi - n_lo;
    float inv = (cnt > 0) ? 1.0f / (float)cnt : 0.f;
    hg[g * D2 + t] = ssum[t] * inv;         // per-graph mean, written once, no atomics
  }
}

// ---------- head ----------
__global__ void __launch_bounds__(128) k_mlp1(const float* __restrict__ hg,
                                              const float* __restrict__ sf,
                                              const float* __restrict__ Wf1,
                                              const float* __restrict__ bf1,
                                              float* __restrict__ y1) {
  __shared__ float prod[D2 * DIM_SF];
  __shared__ float hgl[D2], sfl[DIM_SF];
  int g = blockIdx.x, t = threadIdx.x;
  if (t < D2) hgl[t] = hg[g * D2 + t];
  if (t < DIM_SF) sfl[t] = sf[g * DIM_SF + t];
  __syncthreads();
  for (int i = t; i < D2 * DIM_SF; i += 128) prod[i] = hgl[i >> 5] * sfl[i & 31];
  __syncthreads();
  float acc = bf1[t];
#pragma unroll 4
  for (int k = 0; k < D2 * DIM_SF; k++) acc += prod[k] * Wf1[k * DF1 + t];
  y1[g * DF1 + t] = acc;
}

__global__ void k_bnstats(const float* __restrict__ x, int ld,
                          float* __restrict__ mu, float* __restrict__ rstd) {
  __shared__ float ssum[256], ssq[256];
  int c = blockIdx.x, t = threadIdx.x;
  float s = 0.f, q = 0.f;
  for (int r = t; r < N_GRAPHS; r += 256) { float v = x[r * ld + c]; s += v; q += v * v; }
  ssum[t] = s; ssq[t] = q; __syncthreads();
  for (int off = 128; off > 0; off >>= 1) {
    if (t < off) { ssum[t] += ssum[t + off]; ssq[t] += ssq[t + off]; }
    __syncthreads();
  }
  if (t == 0) {
    float m = ssum[0] / (float)N_GRAPHS;
    float var = ssq[0] / (float)N_GRAPHS - m * m;
    mu[c] = m;
    rstd[c] = rsqrtf(var + EPS);
  }
}

__global__ void k_mlp2(const float* __restrict__ y1, const float* __restrict__ mu1,
                       const float* __restrict__ rstd1, const float* __restrict__ g1,
                       const float* __restrict__ be1, const float* __restrict__ Wf2,
                       const float* __restrict__ bf2, float* __restrict__ y2) {
  int idx = blockIdx.x * 256 + threadIdx.x;
  int g = idx >> 5, o = idx & 31;
  float acc = bf2[o];
  for (int k = 0; k < DF1; k++) {
    float x = (y1[g * DF1 + k] - mu1[k]) * rstd1[k] * g1[k] + be1[k];
    x = fmaxf(x, 0.f);
    acc += x * Wf2[k * DF2 + o];
  }
  y2[g * DF2 + o] = acc;
}

__global__ void k_mlp3(const float* __restrict__ y2, const float* __restrict__ mu2,
                       const float* __restrict__ rstd2, const float* __restrict__ g2,
                       const float* __restrict__ be2, const float* __restrict__ Wf3,
                       const float* __restrict__ bf3, float* __restrict__ out) {
  int idx = blockIdx.x * 256 + threadIdx.x;
  int g = idx >> 3, o = idx & 7;
  float acc = bf3[o];
  for (int k = 0; k < DF2; k++) {
    float x = (y2[g * DF2 + k] - mu2[k]) * rstd2[k] * g2[k] + be2[k];
    x = fmaxf(x, 0.f);
    acc += x * Wf3[k * DOUT + o];
  }
  out[g * DOUT + o] = acc;
}

extern "C" void kernel_launch(void* const* d_in, const int* in_sizes, int n_in,
                              void* d_out, int out_size, void* d_ws, size_t ws_size,
                              hipStream_t stream) {
  const float* feat = (const float*)d_in[0];
  const float* sf   = (const float*)d_in[1];
  const int*   src  = (const int*)d_in[2];
  const int*   dst  = (const int*)d_in[3];
  const int*   n2g  = (const int*)d_in[4];
  const float* W1   = (const float*)d_in[5];
  const float* b1   = (const float*)d_in[6];
  const float* W2   = (const float*)d_in[7];
  const float* b2   = (const float*)d_in[8];
  const float* Wf1  = (const float*)d_in[9];
  const float* bf1  = (const float*)d_in[10];
  const float* g1   = (const float*)d_in[11];
  const float* be1  = (const float*)d_in[12];
  const float* Wf2  = (const float*)d_in[13];
  const float* bf2  = (const float*)d_in[14];
  const float* g2   = (const float*)d_in[15];
  const float* be2  = (const float*)d_in[16];
  const float* Wf3  = (const float*)d_in[17];
  const float* bf3  = (const float*)d_in[18];
  float* out = (float*)d_out;

  char* ws = (char*)d_ws;
  size_t off = 0;
  auto alloc = [&](size_t bytes) -> void* {
    void* p = ws + off;
    off = (off + bytes + 255) & ~(size_t)255;
    return p;
  };
  int*      g_offs   = (int*)alloc((N_GRAPHS + 1) * 4);
  float*    hg       = (float*)alloc(N_GRAPHS * D2 * 4);
  int*      deg      = (int*)alloc(N_NODES * 4);
  int*      row_off  = (int*)alloc(N_NODES * 4);
  int*      counts   = (int*)alloc((size_t)NBLK1 * NBK * 4);
  int*      offs     = (int*)alloc((size_t)NBLK1 * NBK * 4);
  int*      totals   = (int*)alloc(NBK * 4);
  int*      bin_base = (int*)alloc((NBK + 1) * 4);
  unsigned* packed   = (unsigned*)alloc((size_t)N_EDGES * 4);
  int*      csr      = (int*)alloc((size_t)N_EDGES * 4);
  __half*   p1h      = (__half*)alloc((size_t)N_NODES * D1P * 2);
  __half*   p2h      = (__half*)alloc((size_t)N_NODES * D2P * 2);
  float*    y1       = (float*)alloc((size_t)N_GRAPHS * DF1 * 4);
  float*    y2       = (float*)alloc((size_t)N_GRAPHS * DF2 * 4);
  float*    mu1      = (float*)alloc(DF1 * 4);
  float*    rstd1    = (float*)alloc(DF1 * 4);
  float*    mu2      = (float*)alloc(DF2 * 4);
  float*    rstd2    = (float*)alloc(DF2 * 4);

  k_goff<<<(N_GRAPHS + 1 + 255) / 256, 256, 0, stream>>>(n2g, g_offs);
  k_bcount<<<NBLK1, 256, 0, stream>>>(dst, counts);
  k_bscanA<<<NBK, 64, 0, stream>>>(counts, offs, totals);
  k_bscanB<<<1, NBK, 0, stream>>>(totals, bin_base);
  k_bscatter<<<NBLK1, 256, 0, stream>>>(src, dst, offs, bin_base, packed);
  k_bfine<<<NBK, 256, 0, stream>>>(packed, bin_base, csr, deg, row_off);
  k_gemm1<<<N_NODES / 40, 256, 0, stream>>>(feat, W1, p1h);
  k_agg1<<<N_NODES / 4, 256, 0, stream>>>(p1h, deg, row_off, csr, b1, W2, p2h);
  k_agg2<<<N_GRAPHS, 512, 0, stream>>>(p2h, deg, row_off, csr, b2, g_offs, hg);
  k_mlp1<<<N_GRAPHS, 128, 0, stream>>>(hg, sf, Wf1, bf1, y1);
  k_bnstats<<<DF1, 256, 0, stream>>>(y1, DF1, mu1, rstd1);
  k_mlp2<<<(N_GRAPHS * DF2) / 256, 256, 0, stream>>>(y1, mu1, rstd1, g1, be1, Wf2, bf2, y2);
  k_bnstats<<<DF2, 256, 0, stream>>>(y2, DF2, mu2, rstd2);
  k_mlp3<<<(N_GRAPHS * DOUT) / 256, 256, 0, stream>>>(y2, mu2, rstd2, g2, be2, Wf3, bf3, out);
}